// Round 21
// baseline (206.282 us; speedup 1.0000x reference)
//
#include <hip/hip_runtime.h>
#include <hip/hip_bf16.h>

#define N_NODES 50000
#define N_EDGES 500000
#define E_AUG   (N_EDGES + N_NODES)   // 550000 (divisible by 16)
#define NH1 4
#define HID 64
#define C2  64

#define NBUCK  196                    // d >> 8  (50000/256 -> 0..195)
#define BNODES 256
#define BCAP   4096                   // per-bucket capacity (expect ~2560, +30 sigma)

#define NL2B    2048                  // l2 logit/pool blocks
#define L2CHUNK 272                   // 17 iters x 16 edges; 2048*272 >= E_AUG
#define L2BINS  320                   // >= max node span of a 272-slot chunk (fallback ok)

typedef unsigned int uint32;
typedef unsigned short ushort16;
typedef __attribute__((ext_vector_type(8))) short short8v;
typedef __attribute__((ext_vector_type(4))) float f32x4;

__device__ __forceinline__ ushort16 f2bf(float f) {
    union { float f; uint32 u; } v; v.f = f;
    uint32 u = v.u + (0x7FFFu + ((v.u >> 16) & 1u));   // RNE
    return (ushort16)(u >> 16);
}
__device__ __forceinline__ float bf2f(ushort16 h) {
    union { uint32 u; float f; } v; v.u = ((uint32)h) << 16;
    return v.f;
}

// ---------------- prep: zero bcnt + pack all weights ----------------

__global__ void prep_kernel(const float* __restrict__ W1l, const float* __restrict__ b1l,
                            const float* __restrict__ W1r, const float* __restrict__ b1r,
                            const float* __restrict__ W1e, const float* __restrict__ att1,
                            const float* __restrict__ bias1,
                            const float* __restrict__ W2l, const float* __restrict__ W2r,
                            float* __restrict__ Wpack, float* __restrict__ Apack,
                            float4* __restrict__ wpk4, ushort16* __restrict__ Wt,
                            int* __restrict__ bcnt) {
    const int tid = threadIdx.x;
    int t = blockIdx.x * 256 + tid;
    if (blockIdx.x == 0) {
        bcnt[tid] = 0;
        {
            int h = tid >> 6, hc = tid;
            float* wp = &Wpack[((tid & 63) * 4 + h) * 8];
            wp[0] = W1l[hc];       wp[1] = W1l[256 + hc];
            wp[2] = W1r[hc];       wp[3] = W1r[256 + hc];
            wp[4] = W1e[hc];       wp[5] = W1e[256 + hc];
            wp[6] = b1l[hc] + b1r[hc];
            wp[7] = 0.4f * att1[hc];
            wpk4[hc] = make_float4(W1l[hc], W1l[256 + hc], b1l[hc] + bias1[hc], 0.0f);
        }
        if (tid < 28) {
            int h = tid / 7, comp = tid % 7;
            float s = 0.0f;
            for (int c = 0; c < 64; ++c) {
                int hc = h * 64 + c;
                float m;
                switch (comp) {
                    case 0: m = W1l[hc]; break;
                    case 1: m = W1l[256 + hc]; break;
                    case 2: m = W1r[hc]; break;
                    case 3: m = W1r[256 + hc]; break;
                    case 4: m = W1e[hc]; break;
                    case 5: m = W1e[256 + hc]; break;
                    default: m = b1l[hc] + b1r[hc]; break;
                }
                s += att1[hc] * m;
            }
            Apack[h * 8 + comp] = 0.6f * s;
        }
    }
    if (t < 128 * 256) {
        int c = t & 127, k = t >> 7;
        float w = (c < 64) ? W2l[k * 64 + c] : W2r[k * 64 + (c - 64)];
        Wt[c * 256 + k] = f2bf(w);
    }
}

// ---------------- pass1: bucketed staging + fused l1 alpha, 1 edge/thread --------
// Stages: st_meta {s,d,a0,a1}, st_alpha {exp p_h}, st_x {x[s]}.

#define HIST_BLOCKS ((N_EDGES + 255) / 256)   // 1954

__global__ __launch_bounds__(256) void pass1_kernel(
    const int* __restrict__ ei, const float* __restrict__ ea,
    const float* __restrict__ x,
    const float* __restrict__ Wpack, const float* __restrict__ Apack,
    int4* __restrict__ st_meta, float4* __restrict__ st_alpha,
    float2* __restrict__ st_x, int* __restrict__ bcnt) {
    __shared__ float sWp[2048];
    __shared__ float sA[32];
    __shared__ int lbc[NBUCK];
    __shared__ int lbase[NBUCK];
    const int tid = threadIdx.x;
    for (int i = tid; i < 2048; i += 256) sWp[i] = Wpack[i];
    if (tid < 32) sA[tid] = Apack[tid];
    if (tid < NBUCK) lbc[tid] = 0;
    __syncthreads();

    const int e = blockIdx.x * 256 + tid;
    const bool val = (e < N_EDGES);
    int4 rec; int bket = 0, lofs = 0;
    float u0 = 0, u1 = 0, u2 = 0, u3 = 0, u4 = 0, u5 = 0;
    if (val) {
        const int s = ei[e], d = ei[N_EDGES + e];
        const float2 a = *(const float2*)&ea[2 * e];
        rec.x = s; rec.y = d;
        rec.z = __float_as_int(a.x); rec.w = __float_as_int(a.y);
        bket = d >> 8;
        lofs = atomicAdd(&lbc[bket], 1);
        const float2 xs = *(const float2*)&x[2 * s];
        const float2 xd = *(const float2*)&x[2 * d];
        u0 = xs.x; u1 = xs.y; u2 = xd.x; u3 = xd.y; u4 = a.x; u5 = a.y;
    }

    float p[4];
    #pragma unroll
    for (int h = 0; h < 4; ++h)
        p[h] = fmaf(u0, sA[h * 8], fmaf(u1, sA[h * 8 + 1], fmaf(u2, sA[h * 8 + 2],
               fmaf(u3, sA[h * 8 + 3], fmaf(u4, sA[h * 8 + 4],
               fmaf(u5, sA[h * 8 + 5], sA[h * 8 + 6]))))));
    for (int c = 0; c < 64; ++c) {
        const float* wp = &sWp[c * 32];
        #pragma unroll
        for (int h = 0; h < 4; ++h) {
            const float4 wa = *(const float4*)&wp[h * 8];
            const float4 wb = *(const float4*)&wp[h * 8 + 4];
            float tt = fmaf(u0, wa.x, fmaf(u1, wa.y, fmaf(u2, wa.z,
                       fmaf(u3, wa.w, fmaf(u4, wb.x, fmaf(u5, wb.y, wb.z))))));
            p[h] = fmaf(fabsf(tt), wb.w, p[h]);
        }
    }

    __syncthreads();
    if (tid < NBUCK) lbase[tid] = lbc[tid] ? atomicAdd(&bcnt[tid], lbc[tid]) : 0;
    __syncthreads();
    if (val) {
        int pos = bket * BCAP + lbase[bket] + lofs;
        st_meta[pos] = rec;
        st_alpha[pos] = make_float4(__expf(p[0]), __expf(p[1]), __expf(p[2]), __expf(p[3]));
        st_x[pos] = make_float2(u0, u1);
    }
}

// ---------------- bscan: bucket bases (1 block, 256 threads) ----------------

__global__ void bscan_kernel(const int* __restrict__ bcnt, int* __restrict__ bbase,
                             int* __restrict__ offs) {
    __shared__ int s[256];
    int tid = threadIdx.x;
    int nodec = (tid < NBUCK) ? min(BNODES, N_NODES - tid * BNODES) : 0;
    int v = (tid < NBUCK) ? bcnt[tid] + nodec : 0;
    s[tid] = v;
    __syncthreads();
    for (int off = 1; off < 256; off <<= 1) {
        int t = (tid >= off) ? s[tid - off] : 0;
        __syncthreads();
        s[tid] += t;
        __syncthreads();
    }
    if (tid < NBUCK) bbase[tid] = s[tid] - v;   // exclusive
    if (tid == 0) offs[N_NODES] = E_AUG;
}

// ---------------- buildk: histogram + scan + self-loops (incl. self alpha) + scatter

__global__ __launch_bounds__(256) void buildk_kernel(
    const int4* __restrict__ st_meta, const float4* __restrict__ st_alpha,
    const float2* __restrict__ st_x,
    const int* __restrict__ bcnt, const int* __restrict__ bbase,
    const float* __restrict__ xg,
    const float* __restrict__ Wpack, const float* __restrict__ Apack,
    int* __restrict__ offs, float* __restrict__ den,
    int4* __restrict__ epk, float4* __restrict__ af, float2* __restrict__ xsrc) {
    __shared__ int bins[256];
    __shared__ float ls0[256], ls1[256];
    __shared__ int scan[256];
    __shared__ int cursor[256];
    __shared__ float sWp[2048];
    __shared__ float sA[32];
    const int tid = threadIdx.x, bk = blockIdx.x;
    bins[tid] = 0; ls0[tid] = 0.0f; ls1[tid] = 0.0f;
    for (int i = tid; i < 2048; i += 256) sWp[i] = Wpack[i];
    if (tid < 32) sA[tid] = Apack[tid];
    __syncthreads();

    const int n_ = bcnt[bk];
    const int4* sb = st_meta + (size_t)bk * BCAP;
    const float4* sa = st_alpha + (size_t)bk * BCAP;
    const float2* sx = st_x + (size_t)bk * BCAP;
    for (int i = tid; i < n_; i += 256) {
        int4 r = sb[i];
        int li = r.y & 255;
        atomicAdd(&bins[li], 1);
        atomicAdd(&ls0[li], __int_as_float(r.z));
        atomicAdd(&ls1[li], __int_as_float(r.w));
    }
    __syncthreads();

    const int node = bk * BNODES + tid;
    const int v = (node < N_NODES) ? bins[tid] + 1 : 0;
    scan[tid] = v;
    __syncthreads();
    for (int off = 1; off < 256; off <<= 1) {
        int t = (tid >= off) ? scan[tid - off] : 0;
        __syncthreads();
        scan[tid] += t;
        __syncthreads();
    }
    const int o = bbase[bk] + scan[tid] - v;   // exclusive position
    if (node < N_NODES) {
        offs[node] = o;
        den[node] = 0.0f;
        float dgf = (float)max(bins[tid], 1);
        float u4 = ls0[tid] / dgf, u5 = ls1[tid] / dgf;
        int4 sl;
        sl.x = node; sl.y = node;
        sl.z = __float_as_int(u4); sl.w = __float_as_int(u5);
        epk[o] = sl;
        // self alpha (u2=u0, u3=u1)
        const float2 xn = *(const float2*)&xg[2 * node];
        const float u0 = xn.x, u1 = xn.y;
        float4 alf;
        #pragma unroll
        for (int h = 0; h < 4; ++h) {
            float ps = fmaf(u0, sA[h * 8] + sA[h * 8 + 2],
                       fmaf(u1, sA[h * 8 + 1] + sA[h * 8 + 3],
                       fmaf(u4, sA[h * 8 + 4], fmaf(u5, sA[h * 8 + 5], sA[h * 8 + 6]))));
            for (int c = 0; c < 64; ++c) {
                const float* wp = &sWp[c * 32 + h * 8];
                const float4 wa = *(const float4*)wp;
                const float4 wb = *(const float4*)(wp + 4);
                float tt = fmaf(u0, wa.x + wa.z, fmaf(u1, wa.y + wa.w,
                           fmaf(u4, wb.x, fmaf(u5, wb.y, wb.z))));
                ps = fmaf(fabsf(tt), wb.w, ps);
            }
            alf[h] = __expf(ps);
        }
        af[o] = *(float4*)&alf;
        xsrc[o] = xn;
    }
    cursor[tid] = o + 1;                       // first real-edge slot
    __syncthreads();

    for (int i = tid; i < n_; i += 256) {
        int4 r = sb[i];                        // L2-warm
        int pos = atomicAdd(&cursor[r.y & 255], 1);
        epk[pos] = r;
        af[pos] = sa[i];
        xsrc[pos] = sx[i];
    }
}

// ---------------- Fused: l1 softmax-sum (streaming) + h build + MFMA ----------

__global__ __launch_bounds__(256) void l1out_fused_kernel(
    const int* __restrict__ offs, const float4* __restrict__ af,
    const float2* __restrict__ xsrc,
    const float4* __restrict__ wpk4, const ushort16* __restrict__ Wt,
    const float* __restrict__ b2l, const float* __restrict__ b2r,
    ushort16* __restrict__ xl2b, ushort16* __restrict__ xr2b) {
    __shared__ short hlds[64 * 256];    // 32 KB bf16 h tile
    __shared__ float4 swpk[256];        // 4 KB build coeffs
    const int tid = threadIdx.x;
    const int n0 = blockIdx.x * 64;
    const int lane = tid & 63, w = tid >> 6;

    swpk[tid] = wpk4[tid];

    // ---- phase 0: streaming weighted sums for (node, head) ----
    const int nl = tid >> 2, head = tid & 3;
    const int node = n0 + nl;
    float S1 = 0.0f, S2 = 0.0f;
    if (node < N_NODES) {
        const int beg = offs[node], end = offs[node + 1];
        const float* afp = (const float*)af;
        float den = 0.0f, s1 = 0.0f, s2 = 0.0f;
        for (int e = beg; e < end; ++e) {
            float wt = afp[4 * e + head];
            float2 xs = xsrc[e];
            den += wt;
            s1 = fmaf(wt, xs.x, s1);
            s2 = fmaf(wt, xs.y, s2);
        }
        float inv = 1.0f / (den + 1e-16f);
        S1 = s1 * inv;
        S2 = s2 * inv;
    }
    __syncthreads();   // swpk ready

    // ---- phase 1: build h slice ----
    {
        const int kseg = head * 64;
        const int swz = (nl & 7) << 3;
        for (int i = 0; i < 8; ++i) {
            short8v hv;
            #pragma unroll
            for (int j = 0; j < 8; ++j) {
                float4 wv = swpk[kseg + i * 8 + j];
                float g = fmaf(wv.x, S1, fmaf(wv.y, S2, wv.z));
                g = g > 0.0f ? g : (__expf(g) - 1.0f);
                hv[j] = (short)f2bf(g);
            }
            *(short8v*)&hlds[(nl * 256 + kseg + i * 8) ^ swz] = hv;
        }
    }

    // ---- B fragments ----
    short8v bfrag[2][8];
    {
        const int bc = w * 32 + (lane & 15);
        const int k0 = (lane >> 4) * 8;
        #pragma unroll
        for (int ct = 0; ct < 2; ++ct)
            #pragma unroll
            for (int kb = 0; kb < 8; ++kb)
                bfrag[ct][kb] = *(const short8v*)&Wt[(size_t)(bc + ct * 16) * 256 + kb * 32 + k0];
    }
    __syncthreads();

    // ---- phase 2: MFMA ----
    f32x4 acc[4][2];
    #pragma unroll
    for (int rt = 0; rt < 4; ++rt)
        #pragma unroll
        for (int ct = 0; ct < 2; ++ct)
            acc[rt][ct] = (f32x4){0.0f, 0.0f, 0.0f, 0.0f};

    const int arow = lane & 15, ak0 = (lane >> 4) * 8;
    #pragma unroll
    for (int rt = 0; rt < 4; ++rt) {
        const int n = rt * 16 + arow;
        const int swz = (n & 7) << 3;
        #pragma unroll
        for (int kb = 0; kb < 8; ++kb) {
            short8v a = *(const short8v*)&hlds[(n * 256 + kb * 32 + ak0) ^ swz];
            acc[rt][0] = __builtin_amdgcn_mfma_f32_16x16x32_bf16(a, bfrag[0][kb], acc[rt][0], 0, 0, 0);
            acc[rt][1] = __builtin_amdgcn_mfma_f32_16x16x32_bf16(a, bfrag[1][kb], acc[rt][1], 0, 0, 0);
        }
    }

    // ---- epilogue ----
    #pragma unroll
    for (int ct = 0; ct < 2; ++ct) {
        const int c = w * 32 + ct * 16 + (lane & 15);
        const bool isL = (c < 64);
        const int cc = isL ? c : c - 64;
        const float bias = isL ? b2l[cc] : b2r[cc];
        ushort16* dst = isL ? xl2b : xr2b;
        #pragma unroll
        for (int rt = 0; rt < 4; ++rt)
            #pragma unroll
            for (int r = 0; r < 4; ++r) {
                int nn = n0 + rt * 16 + (lane >> 4) * 4 + r;
                if (nn < N_NODES) dst[nn * 64 + cc] = f2bf(acc[rt][ct][r] + bias);
            }
    }
}

// ---------------- Layer 2 logits: exp stored; den via LDS segmented reduction ----

__global__ __launch_bounds__(256) void l2_logit_kernel(
    const ushort16* __restrict__ xl2b, const ushort16* __restrict__ xr2b,
    const int4* __restrict__ epk,
    const float* __restrict__ W2e, const float* __restrict__ att2,
    float* __restrict__ alpha2, float* __restrict__ den) {
    __shared__ float sWe[128], satt[64];
    __shared__ float bins[L2BINS];
    const int tid = threadIdx.x;
    if (tid < 128) sWe[tid] = W2e[tid];
    if (tid < 64) satt[tid] = att2[tid];
    for (int i = tid; i < L2BINS; i += 256) bins[i] = 0.0f;
    const int base = blockIdx.x * L2CHUNK;
    const int d_first = epk[min(base, E_AUG - 1)].y;
    __syncthreads();

    const int lane = tid & 63, w = tid >> 6;
    const int cl = lane & 15, g = lane >> 4;
    const uint32* xlp = (const uint32*)xl2b;
    const uint32* xrp = (const uint32*)xr2b;

    for (int it = 0; it < L2CHUNK / 16; ++it) {
        const int e = base + it * 16 + w * 4 + g;
        if (e < E_AUG) {
            const int4 v = epk[e];
            const float ae0 = __int_as_float(v.z), ae1 = __int_as_float(v.w);
            float acc = 0.0f;
            #pragma unroll
            for (int q = 0; q < 2; ++q) {
                const int c2 = cl + q * 16;
                const uint32 ul = xlp[v.x * 32 + c2];
                const uint32 ur = xrp[v.y * 32 + c2];
                const int c0 = 2 * c2, c1 = 2 * c2 + 1;
                float xl0 = bf2f((ushort16)(ul & 0xffff)), xl1 = bf2f((ushort16)(ul >> 16));
                float xr0 = bf2f((ushort16)(ur & 0xffff)), xr1 = bf2f((ushort16)(ur >> 16));
                float t0 = xl0 + xr0 + fmaf(ae0, sWe[c0], ae1 * sWe[64 + c0]);
                float t1 = xl1 + xr1 + fmaf(ae0, sWe[c1], ae1 * sWe[64 + c1]);
                t0 = t0 > 0.0f ? t0 : 0.2f * t0;
                t1 = t1 > 0.0f ? t1 : 0.2f * t1;
                acc = fmaf(t0, satt[c0], fmaf(t1, satt[c1], acc));
            }
            #pragma unroll
            for (int off = 8; off; off >>= 1) acc += __shfl_xor(acc, off);
            if (cl == 0) {
                float wv = __expf(acc);
                alpha2[e] = wv;
                int rel = v.y - d_first;
                if (rel < L2BINS) atomicAdd(&bins[rel], wv);
                else atomicAdd(&den[v.y], wv);
            }
        }
    }
    __syncthreads();
    for (int i = tid; i < L2BINS; i += 256) {
        float b = bins[i];
        int node = d_first + i;
        if (b != 0.0f && node < N_NODES) atomicAdd(&den[node], b);
    }
}

// ---------------- Layer 2 pool: edge-parallel weighted accumulation ----------------

__global__ __launch_bounds__(256) void l2_pool_kernel(
    const ushort16* __restrict__ xl2b, const int4* __restrict__ epk,
    const float* __restrict__ alpha2, const float* __restrict__ den,
    float* __restrict__ pblock) {
    __shared__ float sp[16][64];
    const int tid = threadIdx.x;
    const int lane = tid & 63, w = tid >> 6;
    const int cl = lane & 15, g = lane >> 4;
    const int slot = w * 4 + g;
    const int base = blockIdx.x * L2CHUNK;
    const uint32* xlp = (const uint32*)xl2b;

    float a0 = 0.0f, a1 = 0.0f, a2 = 0.0f, a3 = 0.0f;
    for (int it = 0; it < L2CHUNK / 16; ++it) {
        const int e = base + it * 16 + w * 4 + g;
        if (e < E_AUG) {
            const int4 v = epk[e];
            const float coef = alpha2[e] / (den[v.y] + 1e-16f);
            const uint32 u0 = xlp[v.x * 32 + cl];
            const uint32 u1 = xlp[v.x * 32 + cl + 16];
            a0 = fmaf(coef, bf2f((ushort16)(u0 & 0xffff)), a0);
            a1 = fmaf(coef, bf2f((ushort16)(u0 >> 16)), a1);
            a2 = fmaf(coef, bf2f((ushort16)(u1 & 0xffff)), a2);
            a3 = fmaf(coef, bf2f((ushort16)(u1 >> 16)), a3);
        }
    }
    sp[slot][2 * cl] = a0;
    sp[slot][2 * cl + 1] = a1;
    sp[slot][2 * cl + 32] = a2;
    sp[slot][2 * cl + 33] = a3;
    __syncthreads();
    if (tid < 64) {
        float s = 0.0f;
        #pragma unroll
        for (int i = 0; i < 16; ++i) s += sp[i][tid];
        pblock[blockIdx.x * 64 + tid] = s;
    }
}

// ---------------- pool: partial (64 blocks) then final (1 block) ----------------

__global__ __launch_bounds__(256) void pool_partial_kernel(const float* __restrict__ pblock,
                                                           float* __restrict__ pfin) {
    __shared__ float s[256];
    int tid = threadIdx.x;
    int l = tid & 63, q = tid >> 6;
    float local = 0.0f;
    for (int r = blockIdx.x * 4 + q; r < NL2B; r += 64 * 4)
        local += pblock[r * 64 + l];
    s[tid] = local;
    __syncthreads();
    if (tid < 64) {
        float v = s[tid] + s[tid + 64] + s[tid + 128] + s[tid + 192];
        pfin[blockIdx.x * 64 + tid] = v;
    }
}

__global__ __launch_bounds__(256) void pool_final2_kernel(const float* __restrict__ pfin,
                                                          const float* __restrict__ bias2,
                                                          float* __restrict__ d_out) {
    __shared__ float s[256];
    int tid = threadIdx.x;
    int l = tid & 63, q = tid >> 6;
    float local = 0.0f;
    for (int r = q; r < 64; r += 4)
        local += pfin[r * 64 + l];
    s[tid] = local;
    __syncthreads();
    if (tid < 64) {
        float v = s[tid] + s[tid + 64] + s[tid + 128] + s[tid + 192];
        d_out[tid] = v * (1.0f / N_NODES) + bias2[tid];
    }
}

// ---------------- Host launch ----------------

extern "C" void kernel_launch(void* const* d_in, const int* in_sizes, int n_in,
                              void* d_out, int out_size, void* d_ws, size_t ws_size,
                              hipStream_t stream) {
    const float* x     = (const float*)d_in[0];
    const float* eattr = (const float*)d_in[1];
    const float* W1l   = (const float*)d_in[2];
    const float* b1l   = (const float*)d_in[3];
    const float* W1r   = (const float*)d_in[4];
    const float* b1r   = (const float*)d_in[5];
    const float* W1e   = (const float*)d_in[6];
    const float* att1  = (const float*)d_in[7];
    const float* bias1 = (const float*)d_in[8];
    const float* W2l   = (const float*)d_in[9];
    const float* b2l   = (const float*)d_in[10];
    const float* W2r   = (const float*)d_in[11];
    const float* b2r   = (const float*)d_in[12];
    const float* W2e   = (const float*)d_in[13];
    const float* att2  = (const float*)d_in[14];
    const float* bias2 = (const float*)d_in[15];
    const int*   ei    = (const int*)d_in[16];
    float* out = (float*)d_out;

    char* p = (char*)d_ws;
    auto alloc = [&](size_t bytes) -> void* {
        void* r = (void*)p;
        p += (bytes + 255) & ~(size_t)255;
        return r;
    };
    int*   bcnt   = (int*)alloc(256 * 4);
    int*   bbase  = (int*)alloc(256 * 4);
    int*   offs   = (int*)alloc((N_NODES + 1) * 4);
    float* den    = (float*)alloc(N_NODES * 4);
    int4*  st_meta  = (int4*)alloc((size_t)NBUCK * BCAP * 16);
    float4* st_alpha = (float4*)alloc((size_t)NBUCK * BCAP * 16);
    float2* st_x  = (float2*)alloc((size_t)NBUCK * BCAP * 8);
    int4*  epk    = (int4*)alloc((size_t)E_AUG * 16);
    float4* af    = (float4*)alloc((size_t)E_AUG * 16);
    float2* xsrc  = (float2*)alloc((size_t)E_AUG * 8);
    float* alpha2 = (float*)alloc((size_t)E_AUG * 4);
    float* Wpack  = (float*)alloc(256 * 8 * 4);
    float* Apack  = (float*)alloc(32 * 4);
    float4* wpk4  = (float4*)alloc(256 * 16);
    ushort16* Wt  = (ushort16*)alloc(128 * 256 * 2);
    ushort16* xl2b = (ushort16*)alloc((size_t)N_NODES * C2 * 2);
    ushort16* xr2b = (ushort16*)alloc((size_t)N_NODES * C2 * 2);
    float* pblock = (float*)alloc((size_t)NL2B * 64 * 4);
    float* pfin   = (float*)alloc((size_t)64 * 64 * 4);

    prep_kernel<<<128, 256, 0, stream>>>(W1l, b1l, W1r, b1r, W1e, att1, bias1, W2l, W2r,
                                         Wpack, Apack, wpk4, Wt, bcnt);

    pass1_kernel<<<HIST_BLOCKS, 256, 0, stream>>>(ei, eattr, x, Wpack, Apack,
                                                  st_meta, st_alpha, st_x, bcnt);

    bscan_kernel<<<1, 256, 0, stream>>>(bcnt, bbase, offs);

    buildk_kernel<<<NBUCK, 256, 0, stream>>>(st_meta, st_alpha, st_x, bcnt, bbase,
                                             x, Wpack, Apack,
                                             offs, den, epk, af, xsrc);

    l1out_fused_kernel<<<(N_NODES + 63) / 64, 256, 0, stream>>>(
        offs, af, xsrc, wpk4, Wt, b2l, b2r, xl2b, xr2b);

    l2_logit_kernel<<<NL2B, 256, 0, stream>>>(xl2b, xr2b, epk, W2e, att2, alpha2, den);

    l2_pool_kernel<<<NL2B, 256, 0, stream>>>(xl2b, epk, alpha2, den, pblock);

    pool_partial_kernel<<<64, 256, 0, stream>>>(pblock, pfin);
    pool_final2_kernel<<<1, 256, 0, stream>>>(pfin, bias2, out);
}

// Round 22
// 177.133 us; speedup vs baseline: 1.1646x; 1.1646x over previous
//
#include <hip/hip_runtime.h>
#include <hip/hip_bf16.h>

#define N_NODES 50000
#define N_EDGES 500000
#define E_AUG   (N_EDGES + N_NODES)   // 550000 (divisible by 16)
#define NH1 4
#define HID 64
#define C2  64

#define NBUCK  196                    // d >> 8  (50000/256 -> 0..195)
#define BNODES 256
#define BCAP   4096                   // per-bucket capacity (expect ~2560, +30 sigma)

#define NL2B    2048                  // l2 logit/pool blocks
#define L2CHUNK 272                   // 17 iters x 16 edges; 2048*272 >= E_AUG
#define L2BINS  320                   // >= max node span of a 272-slot chunk (fallback ok)

typedef unsigned int uint32;
typedef unsigned short ushort16;
typedef __attribute__((ext_vector_type(8))) short short8v;
typedef __attribute__((ext_vector_type(4))) float f32x4;

__device__ __forceinline__ ushort16 f2bf(float f) {
    union { float f; uint32 u; } v; v.f = f;
    uint32 u = v.u + (0x7FFFu + ((v.u >> 16) & 1u));   // RNE
    return (ushort16)(u >> 16);
}
__device__ __forceinline__ float bf2f(ushort16 h) {
    union { uint32 u; float f; } v; v.u = ((uint32)h) << 16;
    return v.f;
}

// ---------------- prep: zero bcnt + pack all weights ----------------

__global__ void prep_kernel(const float* __restrict__ W1l, const float* __restrict__ b1l,
                            const float* __restrict__ W1r, const float* __restrict__ b1r,
                            const float* __restrict__ W1e, const float* __restrict__ att1,
                            const float* __restrict__ bias1,
                            const float* __restrict__ W2l, const float* __restrict__ W2r,
                            float* __restrict__ Wpack, float* __restrict__ Apack,
                            float4* __restrict__ wpk4, ushort16* __restrict__ Wt,
                            int* __restrict__ bcnt) {
    const int tid = threadIdx.x;
    int t = blockIdx.x * 256 + tid;
    if (blockIdx.x == 0) {
        bcnt[tid] = 0;
        {
            int h = tid >> 6, hc = tid;
            float* wp = &Wpack[((tid & 63) * 4 + h) * 8];
            wp[0] = W1l[hc];       wp[1] = W1l[256 + hc];
            wp[2] = W1r[hc];       wp[3] = W1r[256 + hc];
            wp[4] = W1e[hc];       wp[5] = W1e[256 + hc];
            wp[6] = b1l[hc] + b1r[hc];
            wp[7] = 0.4f * att1[hc];
            wpk4[hc] = make_float4(W1l[hc], W1l[256 + hc], b1l[hc] + bias1[hc], 0.0f);
        }
        if (tid < 28) {
            int h = tid / 7, comp = tid % 7;
            float s = 0.0f;
            for (int c = 0; c < 64; ++c) {
                int hc = h * 64 + c;
                float m;
                switch (comp) {
                    case 0: m = W1l[hc]; break;
                    case 1: m = W1l[256 + hc]; break;
                    case 2: m = W1r[hc]; break;
                    case 3: m = W1r[256 + hc]; break;
                    case 4: m = W1e[hc]; break;
                    case 5: m = W1e[256 + hc]; break;
                    default: m = b1l[hc] + b1r[hc]; break;
                }
                s += att1[hc] * m;
            }
            Apack[h * 8 + comp] = 0.6f * s;
        }
    }
    if (t < 128 * 256) {
        int c = t & 127, k = t >> 7;
        float w = (c < 64) ? W2l[k * 64 + c] : W2r[k * 64 + (c - 64)];
        Wt[c * 256 + k] = f2bf(w);
    }
}

// ---------------- pass1: bucketed staging + fused l1 alpha, 2 edges/thread --------
// Stages: st_meta {s,d,a0,a1}, st_alpha {exp p_h}, st_x {x[s]}.

#define HIST_BLOCKS ((N_EDGES / 2 + 255) / 256)   // 977

__global__ __launch_bounds__(256) void pass1_kernel(
    const int* __restrict__ ei, const float* __restrict__ ea,
    const float* __restrict__ x,
    const float* __restrict__ Wpack, const float* __restrict__ Apack,
    int4* __restrict__ st_meta, float4* __restrict__ st_alpha,
    float2* __restrict__ st_x, int* __restrict__ bcnt) {
    __shared__ float sWp[2048];
    __shared__ float sA[32];
    __shared__ int lbc[NBUCK];
    __shared__ int lbase[NBUCK];
    const int tid = threadIdx.x;
    for (int i = tid; i < 2048; i += 256) sWp[i] = Wpack[i];
    if (tid < 32) sA[tid] = Apack[tid];
    if (tid < NBUCK) lbc[tid] = 0;
    __syncthreads();

    const int e0 = (blockIdx.x * 256 + tid) * 2;
    int4 rec[2]; int bket[2], lofs[2];
    bool val[2];
    float u0[2], u1[2], u2[2], u3[2], u4[2], u5[2];
    #pragma unroll
    for (int j = 0; j < 2; ++j) {
        const int e = e0 + j;
        val[j] = (e < N_EDGES);
        if (val[j]) {
            const int s = ei[e], d = ei[N_EDGES + e];
            const float2 a = *(const float2*)&ea[2 * e];
            rec[j].x = s; rec[j].y = d;
            rec[j].z = __float_as_int(a.x); rec[j].w = __float_as_int(a.y);
            bket[j] = d >> 8;
            lofs[j] = atomicAdd(&lbc[bket[j]], 1);
            const float2 xs = *(const float2*)&x[2 * s];
            const float2 xd = *(const float2*)&x[2 * d];
            u0[j] = xs.x; u1[j] = xs.y; u2[j] = xd.x; u3[j] = xd.y;
            u4[j] = a.x;  u5[j] = a.y;
        } else {
            u0[j] = u1[j] = u2[j] = u3[j] = u4[j] = u5[j] = 0.0f;
        }
    }

    float p[4][2];
    #pragma unroll
    for (int h = 0; h < 4; ++h) {
        const float a0 = sA[h * 8], a1 = sA[h * 8 + 1], a2 = sA[h * 8 + 2],
                    a3 = sA[h * 8 + 3], a4 = sA[h * 8 + 4], a5 = sA[h * 8 + 5],
                    a6 = sA[h * 8 + 6];
        #pragma unroll
        for (int j = 0; j < 2; ++j)
            p[h][j] = fmaf(u0[j], a0, fmaf(u1[j], a1, fmaf(u2[j], a2,
                      fmaf(u3[j], a3, fmaf(u4[j], a4, fmaf(u5[j], a5, a6))))));
    }
    for (int c = 0; c < 64; ++c) {
        const float* wp = &sWp[c * 32];
        #pragma unroll
        for (int h = 0; h < 4; ++h) {
            const float4 wa = *(const float4*)&wp[h * 8];
            const float4 wb = *(const float4*)&wp[h * 8 + 4];
            #pragma unroll
            for (int j = 0; j < 2; ++j) {
                float tt = fmaf(u0[j], wa.x, fmaf(u1[j], wa.y, fmaf(u2[j], wa.z,
                           fmaf(u3[j], wa.w, fmaf(u4[j], wb.x, fmaf(u5[j], wb.y, wb.z))))));
                p[h][j] = fmaf(fabsf(tt), wb.w, p[h][j]);
            }
        }
    }

    __syncthreads();
    if (tid < NBUCK) lbase[tid] = lbc[tid] ? atomicAdd(&bcnt[tid], lbc[tid]) : 0;
    __syncthreads();
    #pragma unroll
    for (int j = 0; j < 2; ++j)
        if (val[j]) {
            int pos = bket[j] * BCAP + lbase[bket[j]] + lofs[j];
            st_meta[pos] = rec[j];
            st_alpha[pos] = make_float4(__expf(p[0][j]), __expf(p[1][j]),
                                        __expf(p[2][j]), __expf(p[3][j]));
            st_x[pos] = make_float2(u0[j], u1[j]);
        }
}

// ---------------- bscan: bucket bases (1 block, 256 threads) ----------------

__global__ void bscan_kernel(const int* __restrict__ bcnt, int* __restrict__ bbase,
                             int* __restrict__ offs) {
    __shared__ int s[256];
    int tid = threadIdx.x;
    int nodec = (tid < NBUCK) ? min(BNODES, N_NODES - tid * BNODES) : 0;
    int v = (tid < NBUCK) ? bcnt[tid] + nodec : 0;
    s[tid] = v;
    __syncthreads();
    for (int off = 1; off < 256; off <<= 1) {
        int t = (tid >= off) ? s[tid - off] : 0;
        __syncthreads();
        s[tid] += t;
        __syncthreads();
    }
    if (tid < NBUCK) bbase[tid] = s[tid] - v;   // exclusive
    if (tid == 0) offs[N_NODES] = E_AUG;
}

// ---------------- buildk: histogram + scan + self-loops (incl. self alpha) + scatter

__global__ __launch_bounds__(256) void buildk_kernel(
    const int4* __restrict__ st_meta, const float4* __restrict__ st_alpha,
    const float2* __restrict__ st_x,
    const int* __restrict__ bcnt, const int* __restrict__ bbase,
    const float* __restrict__ xg,
    const float* __restrict__ Wpack, const float* __restrict__ Apack,
    int* __restrict__ offs, float* __restrict__ den,
    int4* __restrict__ epk, float4* __restrict__ af, float2* __restrict__ xsrc) {
    __shared__ int bins[256];
    __shared__ float ls0[256], ls1[256];
    __shared__ int scan[256];
    __shared__ int cursor[256];
    __shared__ float sWp[2048];
    __shared__ float sA[32];
    const int tid = threadIdx.x, bk = blockIdx.x;
    bins[tid] = 0; ls0[tid] = 0.0f; ls1[tid] = 0.0f;
    for (int i = tid; i < 2048; i += 256) sWp[i] = Wpack[i];
    if (tid < 32) sA[tid] = Apack[tid];
    __syncthreads();

    const int n_ = bcnt[bk];
    const int4* sb = st_meta + (size_t)bk * BCAP;
    const float4* sa = st_alpha + (size_t)bk * BCAP;
    const float2* sx = st_x + (size_t)bk * BCAP;
    for (int i = tid; i < n_; i += 256) {
        int4 r = sb[i];
        int li = r.y & 255;
        atomicAdd(&bins[li], 1);
        atomicAdd(&ls0[li], __int_as_float(r.z));
        atomicAdd(&ls1[li], __int_as_float(r.w));
    }
    __syncthreads();

    const int node = bk * BNODES + tid;
    const int v = (node < N_NODES) ? bins[tid] + 1 : 0;
    scan[tid] = v;
    __syncthreads();
    for (int off = 1; off < 256; off <<= 1) {
        int t = (tid >= off) ? scan[tid - off] : 0;
        __syncthreads();
        scan[tid] += t;
        __syncthreads();
    }
    const int o = bbase[bk] + scan[tid] - v;   // exclusive position
    if (node < N_NODES) {
        offs[node] = o;
        den[node] = 0.0f;
        float dgf = (float)max(bins[tid], 1);
        float u4 = ls0[tid] / dgf, u5 = ls1[tid] / dgf;
        int4 sl;
        sl.x = node; sl.y = node;
        sl.z = __float_as_int(u4); sl.w = __float_as_int(u5);
        epk[o] = sl;
        // self alpha (u2=u0, u3=u1)
        const float2 xn = *(const float2*)&xg[2 * node];
        const float u0 = xn.x, u1 = xn.y;
        float4 alf;
        #pragma unroll
        for (int h = 0; h < 4; ++h) {
            float ps = fmaf(u0, sA[h * 8] + sA[h * 8 + 2],
                       fmaf(u1, sA[h * 8 + 1] + sA[h * 8 + 3],
                       fmaf(u4, sA[h * 8 + 4], fmaf(u5, sA[h * 8 + 5], sA[h * 8 + 6]))));
            for (int c = 0; c < 64; ++c) {
                const float* wp = &sWp[c * 32 + h * 8];
                const float4 wa = *(const float4*)wp;
                const float4 wb = *(const float4*)(wp + 4);
                float tt = fmaf(u0, wa.x + wa.z, fmaf(u1, wa.y + wa.w,
                           fmaf(u4, wb.x, fmaf(u5, wb.y, wb.z))));
                ps = fmaf(fabsf(tt), wb.w, ps);
            }
            alf[h] = __expf(ps);
        }
        af[o] = *(float4*)&alf;
        xsrc[o] = xn;
    }
    cursor[tid] = o + 1;                       // first real-edge slot
    __syncthreads();

    for (int i = tid; i < n_; i += 256) {
        int4 r = sb[i];                        // L2-warm
        int pos = atomicAdd(&cursor[r.y & 255], 1);
        epk[pos] = r;
        af[pos] = sa[i];
        xsrc[pos] = sx[i];
    }
}

// ---------------- Fused: l1 softmax-sum (streaming) + h build + MFMA ----------

__global__ __launch_bounds__(256) void l1out_fused_kernel(
    const int* __restrict__ offs, const float4* __restrict__ af,
    const float2* __restrict__ xsrc,
    const float4* __restrict__ wpk4, const ushort16* __restrict__ Wt,
    const float* __restrict__ b2l, const float* __restrict__ b2r,
    ushort16* __restrict__ xl2b, ushort16* __restrict__ xr2b) {
    __shared__ short hlds[64 * 256];    // 32 KB bf16 h tile
    __shared__ float4 swpk[256];        // 4 KB build coeffs
    const int tid = threadIdx.x;
    const int n0 = blockIdx.x * 64;
    const int lane = tid & 63, w = tid >> 6;

    swpk[tid] = wpk4[tid];

    // ---- phase 0: streaming weighted sums for (node, head) ----
    const int nl = tid >> 2, head = tid & 3;
    const int node = n0 + nl;
    float S1 = 0.0f, S2 = 0.0f;
    if (node < N_NODES) {
        const int beg = offs[node], end = offs[node + 1];
        const float* afp = (const float*)af;
        float den = 0.0f, s1 = 0.0f, s2 = 0.0f;
        for (int e = beg; e < end; ++e) {
            float wt = afp[4 * e + head];
            float2 xs = xsrc[e];
            den += wt;
            s1 = fmaf(wt, xs.x, s1);
            s2 = fmaf(wt, xs.y, s2);
        }
        float inv = 1.0f / (den + 1e-16f);
        S1 = s1 * inv;
        S2 = s2 * inv;
    }
    __syncthreads();   // swpk ready

    // ---- phase 1: build h slice ----
    {
        const int kseg = head * 64;
        const int swz = (nl & 7) << 3;
        for (int i = 0; i < 8; ++i) {
            short8v hv;
            #pragma unroll
            for (int j = 0; j < 8; ++j) {
                float4 wv = swpk[kseg + i * 8 + j];
                float g = fmaf(wv.x, S1, fmaf(wv.y, S2, wv.z));
                g = g > 0.0f ? g : (__expf(g) - 1.0f);
                hv[j] = (short)f2bf(g);
            }
            *(short8v*)&hlds[(nl * 256 + kseg + i * 8) ^ swz] = hv;
        }
    }

    // ---- B fragments ----
    short8v bfrag[2][8];
    {
        const int bc = w * 32 + (lane & 15);
        const int k0 = (lane >> 4) * 8;
        #pragma unroll
        for (int ct = 0; ct < 2; ++ct)
            #pragma unroll
            for (int kb = 0; kb < 8; ++kb)
                bfrag[ct][kb] = *(const short8v*)&Wt[(size_t)(bc + ct * 16) * 256 + kb * 32 + k0];
    }
    __syncthreads();

    // ---- phase 2: MFMA ----
    f32x4 acc[4][2];
    #pragma unroll
    for (int rt = 0; rt < 4; ++rt)
        #pragma unroll
        for (int ct = 0; ct < 2; ++ct)
            acc[rt][ct] = (f32x4){0.0f, 0.0f, 0.0f, 0.0f};

    const int arow = lane & 15, ak0 = (lane >> 4) * 8;
    #pragma unroll
    for (int rt = 0; rt < 4; ++rt) {
        const int n = rt * 16 + arow;
        const int swz = (n & 7) << 3;
        #pragma unroll
        for (int kb = 0; kb < 8; ++kb) {
            short8v a = *(const short8v*)&hlds[(n * 256 + kb * 32 + ak0) ^ swz];
            acc[rt][0] = __builtin_amdgcn_mfma_f32_16x16x32_bf16(a, bfrag[0][kb], acc[rt][0], 0, 0, 0);
            acc[rt][1] = __builtin_amdgcn_mfma_f32_16x16x32_bf16(a, bfrag[1][kb], acc[rt][1], 0, 0, 0);
        }
    }

    // ---- epilogue ----
    #pragma unroll
    for (int ct = 0; ct < 2; ++ct) {
        const int c = w * 32 + ct * 16 + (lane & 15);
        const bool isL = (c < 64);
        const int cc = isL ? c : c - 64;
        const float bias = isL ? b2l[cc] : b2r[cc];
        ushort16* dst = isL ? xl2b : xr2b;
        #pragma unroll
        for (int rt = 0; rt < 4; ++rt)
            #pragma unroll
            for (int r = 0; r < 4; ++r) {
                int nn = n0 + rt * 16 + (lane >> 4) * 4 + r;
                if (nn < N_NODES) dst[nn * 64 + cc] = f2bf(acc[rt][ct][r] + bias);
            }
    }
}

// ---------------- Layer 2 logits: exp stored; den via LDS segmented reduction ----

__global__ __launch_bounds__(256) void l2_logit_kernel(
    const ushort16* __restrict__ xl2b, const ushort16* __restrict__ xr2b,
    const int4* __restrict__ epk,
    const float* __restrict__ W2e, const float* __restrict__ att2,
    float* __restrict__ alpha2, float* __restrict__ den) {
    __shared__ float sWe[128], satt[64];
    __shared__ float bins[L2BINS];
    const int tid = threadIdx.x;
    if (tid < 128) sWe[tid] = W2e[tid];
    if (tid < 64) satt[tid] = att2[tid];
    for (int i = tid; i < L2BINS; i += 256) bins[i] = 0.0f;
    const int base = blockIdx.x * L2CHUNK;
    const int d_first = epk[min(base, E_AUG - 1)].y;
    __syncthreads();

    const int lane = tid & 63, w = tid >> 6;
    const int cl = lane & 15, g = lane >> 4;
    const uint32* xlp = (const uint32*)xl2b;
    const uint32* xrp = (const uint32*)xr2b;

    for (int it = 0; it < L2CHUNK / 16; ++it) {
        const int e = base + it * 16 + w * 4 + g;
        if (e < E_AUG) {
            const int4 v = epk[e];
            const float ae0 = __int_as_float(v.z), ae1 = __int_as_float(v.w);
            float acc = 0.0f;
            #pragma unroll
            for (int q = 0; q < 2; ++q) {
                const int c2 = cl + q * 16;
                const uint32 ul = xlp[v.x * 32 + c2];
                const uint32 ur = xrp[v.y * 32 + c2];
                const int c0 = 2 * c2, c1 = 2 * c2 + 1;
                float xl0 = bf2f((ushort16)(ul & 0xffff)), xl1 = bf2f((ushort16)(ul >> 16));
                float xr0 = bf2f((ushort16)(ur & 0xffff)), xr1 = bf2f((ushort16)(ur >> 16));
                float t0 = xl0 + xr0 + fmaf(ae0, sWe[c0], ae1 * sWe[64 + c0]);
                float t1 = xl1 + xr1 + fmaf(ae0, sWe[c1], ae1 * sWe[64 + c1]);
                t0 = t0 > 0.0f ? t0 : 0.2f * t0;
                t1 = t1 > 0.0f ? t1 : 0.2f * t1;
                acc = fmaf(t0, satt[c0], fmaf(t1, satt[c1], acc));
            }
            #pragma unroll
            for (int off = 8; off; off >>= 1) acc += __shfl_xor(acc, off);
            if (cl == 0) {
                float wv = __expf(acc);
                alpha2[e] = wv;
                int rel = v.y - d_first;
                if (rel < L2BINS) atomicAdd(&bins[rel], wv);
                else atomicAdd(&den[v.y], wv);
            }
        }
    }
    __syncthreads();
    for (int i = tid; i < L2BINS; i += 256) {
        float b = bins[i];
        int node = d_first + i;
        if (b != 0.0f && node < N_NODES) atomicAdd(&den[node], b);
    }
}

// ---------------- Layer 2 pool: edge-parallel weighted accumulation ----------------

__global__ __launch_bounds__(256) void l2_pool_kernel(
    const ushort16* __restrict__ xl2b, const int4* __restrict__ epk,
    const float* __restrict__ alpha2, const float* __restrict__ den,
    float* __restrict__ pblock) {
    __shared__ float sp[16][64];
    const int tid = threadIdx.x;
    const int lane = tid & 63, w = tid >> 6;
    const int cl = lane & 15, g = lane >> 4;
    const int slot = w * 4 + g;
    const int base = blockIdx.x * L2CHUNK;
    const uint32* xlp = (const uint32*)xl2b;

    float a0 = 0.0f, a1 = 0.0f, a2 = 0.0f, a3 = 0.0f;
    for (int it = 0; it < L2CHUNK / 16; ++it) {
        const int e = base + it * 16 + w * 4 + g;
        if (e < E_AUG) {
            const int4 v = epk[e];
            const float coef = alpha2[e] / (den[v.y] + 1e-16f);
            const uint32 u0 = xlp[v.x * 32 + cl];
            const uint32 u1 = xlp[v.x * 32 + cl + 16];
            a0 = fmaf(coef, bf2f((ushort16)(u0 & 0xffff)), a0);
            a1 = fmaf(coef, bf2f((ushort16)(u0 >> 16)), a1);
            a2 = fmaf(coef, bf2f((ushort16)(u1 & 0xffff)), a2);
            a3 = fmaf(coef, bf2f((ushort16)(u1 >> 16)), a3);
        }
    }
    sp[slot][2 * cl] = a0;
    sp[slot][2 * cl + 1] = a1;
    sp[slot][2 * cl + 32] = a2;
    sp[slot][2 * cl + 33] = a3;
    __syncthreads();
    if (tid < 64) {
        float s = 0.0f;
        #pragma unroll
        for (int i = 0; i < 16; ++i) s += sp[i][tid];
        pblock[blockIdx.x * 64 + tid] = s;
    }
}

// ---------------- pool: partial (64 blocks) then final (1 block) ----------------

__global__ __launch_bounds__(256) void pool_partial_kernel(const float* __restrict__ pblock,
                                                           float* __restrict__ pfin) {
    __shared__ float s[256];
    int tid = threadIdx.x;
    int l = tid & 63, q = tid >> 6;
    float local = 0.0f;
    for (int r = blockIdx.x * 4 + q; r < NL2B; r += 64 * 4)
        local += pblock[r * 64 + l];
    s[tid] = local;
    __syncthreads();
    if (tid < 64) {
        float v = s[tid] + s[tid + 64] + s[tid + 128] + s[tid + 192];
        pfin[blockIdx.x * 64 + tid] = v;
    }
}

__global__ __launch_bounds__(256) void pool_final2_kernel(const float* __restrict__ pfin,
                                                          const float* __restrict__ bias2,
                                                          float* __restrict__ d_out) {
    __shared__ float s[256];
    int tid = threadIdx.x;
    int l = tid & 63, q = tid >> 6;
    float local = 0.0f;
    for (int r = q; r < 64; r += 4)
        local += pfin[r * 64 + l];
    s[tid] = local;
    __syncthreads();
    if (tid < 64) {
        float v = s[tid] + s[tid + 64] + s[tid + 128] + s[tid + 192];
        d_out[tid] = v * (1.0f / N_NODES) + bias2[tid];
    }
}

// ---------------- Host launch ----------------

extern "C" void kernel_launch(void* const* d_in, const int* in_sizes, int n_in,
                              void* d_out, int out_size, void* d_ws, size_t ws_size,
                              hipStream_t stream) {
    const float* x     = (const float*)d_in[0];
    const float* eattr = (const float*)d_in[1];
    const float* W1l   = (const float*)d_in[2];
    const float* b1l   = (const float*)d_in[3];
    const float* W1r   = (const float*)d_in[4];
    const float* b1r   = (const float*)d_in[5];
    const float* W1e   = (const float*)d_in[6];
    const float* att1  = (const float*)d_in[7];
    const float* bias1 = (const float*)d_in[8];
    const float* W2l   = (const float*)d_in[9];
    const float* b2l   = (const float*)d_in[10];
    const float* W2r   = (const float*)d_in[11];
    const float* b2r   = (const float*)d_in[12];
    const float* W2e   = (const float*)d_in[13];
    const float* att2  = (const float*)d_in[14];
    const float* bias2 = (const float*)d_in[15];
    const int*   ei    = (const int*)d_in[16];
    float* out = (float*)d_out;

    char* p = (char*)d_ws;
    auto alloc = [&](size_t bytes) -> void* {
        void* r = (void*)p;
        p += (bytes + 255) & ~(size_t)255;
        return r;
    };
    int*   bcnt   = (int*)alloc(256 * 4);
    int*   bbase  = (int*)alloc(256 * 4);
    int*   offs   = (int*)alloc((N_NODES + 1) * 4);
    float* den    = (float*)alloc(N_NODES * 4);
    int4*  st_meta  = (int4*)alloc((size_t)NBUCK * BCAP * 16);
    float4* st_alpha = (float4*)alloc((size_t)NBUCK * BCAP * 16);
    float2* st_x  = (float2*)alloc((size_t)NBUCK * BCAP * 8);
    int4*  epk    = (int4*)alloc((size_t)E_AUG * 16);
    float4* af    = (float4*)alloc((size_t)E_AUG * 16);
    float2* xsrc  = (float2*)alloc((size_t)E_AUG * 8);
    float* alpha2 = (float*)alloc((size_t)E_AUG * 4);
    float* Wpack  = (float*)alloc(256 * 8 * 4);
    float* Apack  = (float*)alloc(32 * 4);
    float4* wpk4  = (float4*)alloc(256 * 16);
    ushort16* Wt  = (ushort16*)alloc(128 * 256 * 2);
    ushort16* xl2b = (ushort16*)alloc((size_t)N_NODES * C2 * 2);
    ushort16* xr2b = (ushort16*)alloc((size_t)N_NODES * C2 * 2);
    float* pblock = (float*)alloc((size_t)NL2B * 64 * 4);
    float* pfin   = (float*)alloc((size_t)64 * 64 * 4);

    prep_kernel<<<128, 256, 0, stream>>>(W1l, b1l, W1r, b1r, W1e, att1, bias1, W2l, W2r,
                                         Wpack, Apack, wpk4, Wt, bcnt);

    pass1_kernel<<<HIST_BLOCKS, 256, 0, stream>>>(ei, eattr, x, Wpack, Apack,
                                                  st_meta, st_alpha, st_x, bcnt);

    bscan_kernel<<<1, 256, 0, stream>>>(bcnt, bbase, offs);

    buildk_kernel<<<NBUCK, 256, 0, stream>>>(st_meta, st_alpha, st_x, bcnt, bbase,
                                             x, Wpack, Apack,
                                             offs, den, epk, af, xsrc);

    l1out_fused_kernel<<<(N_NODES + 63) / 64, 256, 0, stream>>>(
        offs, af, xsrc, wpk4, Wt, b2l, b2r, xl2b, xr2b);

    l2_logit_kernel<<<NL2B, 256, 0, stream>>>(xl2b, xr2b, epk, W2e, att2, alpha2, den);

    l2_pool_kernel<<<NL2B, 256, 0, stream>>>(xl2b, epk, alpha2, den, pblock);

    pool_partial_kernel<<<64, 256, 0, stream>>>(pblock, pfin);
    pool_final2_kernel<<<1, 256, 0, stream>>>(pfin, bias2, out);
}

// Round 23
// 177.001 us; speedup vs baseline: 1.1654x; 1.0007x over previous
//
#include <hip/hip_runtime.h>
#include <hip/hip_bf16.h>

#define N_NODES 50000
#define N_EDGES 500000
#define E_AUG   (N_EDGES + N_NODES)   // 550000 (divisible by 16)
#define NH1 4
#define HID 64
#define C2  64

#define NBUCK  196                    // d >> 8  (50000/256 -> 0..195)
#define BNODES 256
#define BCAP   4096                   // per-bucket capacity (expect ~2560, +30 sigma)

#define NL2B    2048                  // l2 logit/pool blocks
#define L2CHUNK 272                   // 17 iters x 16 edges; 2048*272 >= E_AUG
#define L2BINS  320                   // >= max node span of a 272-slot chunk (fallback ok)

typedef unsigned int uint32;
typedef unsigned short ushort16;
typedef __attribute__((ext_vector_type(8))) short short8v;
typedef __attribute__((ext_vector_type(4))) float f32x4;
typedef __attribute__((ext_vector_type(2))) float f32x2;

__device__ __forceinline__ ushort16 f2bf(float f) {
    union { float f; uint32 u; } v; v.f = f;
    uint32 u = v.u + (0x7FFFu + ((v.u >> 16) & 1u));   // RNE
    return (ushort16)(u >> 16);
}
__device__ __forceinline__ float bf2f(ushort16 h) {
    union { uint32 u; float f; } v; v.u = ((uint32)h) << 16;
    return v.f;
}

// ---------------- prep: zero bcnt + pack all weights ----------------

__global__ void prep_kernel(const float* __restrict__ W1l, const float* __restrict__ b1l,
                            const float* __restrict__ W1r, const float* __restrict__ b1r,
                            const float* __restrict__ W1e, const float* __restrict__ att1,
                            const float* __restrict__ bias1,
                            const float* __restrict__ W2l, const float* __restrict__ W2r,
                            float* __restrict__ Wpack, float* __restrict__ Apack,
                            float4* __restrict__ wpk4, ushort16* __restrict__ Wt,
                            int* __restrict__ bcnt) {
    const int tid = threadIdx.x;
    int t = blockIdx.x * 256 + tid;
    if (blockIdx.x == 0) {
        bcnt[tid] = 0;
        {
            int h = tid >> 6, hc = tid;
            float* wp = &Wpack[((tid & 63) * 4 + h) * 8];
            wp[0] = W1l[hc];       wp[1] = W1l[256 + hc];
            wp[2] = W1r[hc];       wp[3] = W1r[256 + hc];
            wp[4] = W1e[hc];       wp[5] = W1e[256 + hc];
            wp[6] = b1l[hc] + b1r[hc];
            wp[7] = 0.4f * att1[hc];
            wpk4[hc] = make_float4(W1l[hc], W1l[256 + hc], b1l[hc] + bias1[hc], 0.0f);
        }
        if (tid < 28) {
            int h = tid / 7, comp = tid % 7;
            float s = 0.0f;
            for (int c = 0; c < 64; ++c) {
                int hc = h * 64 + c;
                float m;
                switch (comp) {
                    case 0: m = W1l[hc]; break;
                    case 1: m = W1l[256 + hc]; break;
                    case 2: m = W1r[hc]; break;
                    case 3: m = W1r[256 + hc]; break;
                    case 4: m = W1e[hc]; break;
                    case 5: m = W1e[256 + hc]; break;
                    default: m = b1l[hc] + b1r[hc]; break;
                }
                s += att1[hc] * m;
            }
            Apack[h * 8 + comp] = 0.6f * s;
        }
    }
    if (t < 128 * 256) {
        int c = t & 127, k = t >> 7;
        float w = (c < 64) ? W2l[k * 64 + c] : W2r[k * 64 + (c - 64)];
        Wt[c * 256 + k] = f2bf(w);
    }
}

// ---------------- pass1: bucketed staging + fused l1 alpha, 2 edges/thread --------
// Packed f32x2 math: edge j = packed lane -> v_pk_fma_f32.

#define HIST_BLOCKS ((N_EDGES / 2 + 255) / 256)   // 977

__global__ __launch_bounds__(256) void pass1_kernel(
    const int* __restrict__ ei, const float* __restrict__ ea,
    const float* __restrict__ x,
    const float* __restrict__ Wpack, const float* __restrict__ Apack,
    int4* __restrict__ st_meta, float4* __restrict__ st_alpha,
    float2* __restrict__ st_x, int* __restrict__ bcnt) {
    __shared__ float sWp[2048];
    __shared__ float sA[32];
    __shared__ int lbc[NBUCK];
    __shared__ int lbase[NBUCK];
    const int tid = threadIdx.x;
    for (int i = tid; i < 2048; i += 256) sWp[i] = Wpack[i];
    if (tid < 32) sA[tid] = Apack[tid];
    if (tid < NBUCK) lbc[tid] = 0;
    __syncthreads();

    const int e0 = (blockIdx.x * 256 + tid) * 2;
    int4 rec[2]; int bket[2], lofs[2];
    bool val[2];
    f32x2 U0 = {0, 0}, U1 = {0, 0}, U2 = {0, 0}, U3 = {0, 0}, U4 = {0, 0}, U5 = {0, 0};
    #pragma unroll
    for (int j = 0; j < 2; ++j) {
        const int e = e0 + j;
        val[j] = (e < N_EDGES);
        if (val[j]) {
            const int s = ei[e], d = ei[N_EDGES + e];
            const float2 a = *(const float2*)&ea[2 * e];
            rec[j].x = s; rec[j].y = d;
            rec[j].z = __float_as_int(a.x); rec[j].w = __float_as_int(a.y);
            bket[j] = d >> 8;
            lofs[j] = atomicAdd(&lbc[bket[j]], 1);
            const float2 xs = *(const float2*)&x[2 * s];
            const float2 xd = *(const float2*)&x[2 * d];
            U0[j] = xs.x; U1[j] = xs.y; U2[j] = xd.x; U3[j] = xd.y;
            U4[j] = a.x;  U5[j] = a.y;
        }
    }

    f32x2 P[4];
    #pragma unroll
    for (int h = 0; h < 4; ++h)
        P[h] = U0 * sA[h * 8] + U1 * sA[h * 8 + 1] + U2 * sA[h * 8 + 2] +
               U3 * sA[h * 8 + 3] + U4 * sA[h * 8 + 4] + U5 * sA[h * 8 + 5] +
               sA[h * 8 + 6];

    for (int c = 0; c < 64; ++c) {
        const float* wp = &sWp[c * 32];
        #pragma unroll
        for (int h = 0; h < 4; ++h) {
            const float4 wa = *(const float4*)&wp[h * 8];
            const float4 wb = *(const float4*)&wp[h * 8 + 4];
            f32x2 tt = U0 * wa.x + U1 * wa.y + U2 * wa.z + U3 * wa.w +
                       U4 * wb.x + U5 * wb.y + wb.z;
            f32x2 ta = __builtin_elementwise_abs(tt);
            P[h] = ta * wb.w + P[h];
        }
    }

    __syncthreads();
    if (tid < NBUCK) lbase[tid] = lbc[tid] ? atomicAdd(&bcnt[tid], lbc[tid]) : 0;
    __syncthreads();
    #pragma unroll
    for (int j = 0; j < 2; ++j)
        if (val[j]) {
            int pos = bket[j] * BCAP + lbase[bket[j]] + lofs[j];
            st_meta[pos] = rec[j];
            st_alpha[pos] = make_float4(__expf(P[0][j]), __expf(P[1][j]),
                                        __expf(P[2][j]), __expf(P[3][j]));
            st_x[pos] = make_float2(U0[j], U1[j]);
        }
}

// ---------------- bscan: bucket bases (1 block, 256 threads) ----------------

__global__ void bscan_kernel(const int* __restrict__ bcnt, int* __restrict__ bbase,
                             int* __restrict__ offs) {
    __shared__ int s[256];
    int tid = threadIdx.x;
    int nodec = (tid < NBUCK) ? min(BNODES, N_NODES - tid * BNODES) : 0;
    int v = (tid < NBUCK) ? bcnt[tid] + nodec : 0;
    s[tid] = v;
    __syncthreads();
    for (int off = 1; off < 256; off <<= 1) {
        int t = (tid >= off) ? s[tid - off] : 0;
        __syncthreads();
        s[tid] += t;
        __syncthreads();
    }
    if (tid < NBUCK) bbase[tid] = s[tid] - v;   // exclusive
    if (tid == 0) offs[N_NODES] = E_AUG;
}

// ---------------- buildk: histogram + scan + self-loops (incl. self alpha) + scatter

__global__ __launch_bounds__(256) void buildk_kernel(
    const int4* __restrict__ st_meta, const float4* __restrict__ st_alpha,
    const float2* __restrict__ st_x,
    const int* __restrict__ bcnt, const int* __restrict__ bbase,
    const float* __restrict__ xg,
    const float* __restrict__ Wpack, const float* __restrict__ Apack,
    int* __restrict__ offs, float* __restrict__ den,
    int4* __restrict__ epk, float4* __restrict__ af, float2* __restrict__ xsrc) {
    __shared__ int bins[256];
    __shared__ float ls0[256], ls1[256];
    __shared__ int scan[256];
    __shared__ int cursor[256];
    __shared__ float sWp[2048];
    __shared__ float sA[32];
    const int tid = threadIdx.x, bk = blockIdx.x;
    bins[tid] = 0; ls0[tid] = 0.0f; ls1[tid] = 0.0f;
    for (int i = tid; i < 2048; i += 256) sWp[i] = Wpack[i];
    if (tid < 32) sA[tid] = Apack[tid];
    __syncthreads();

    const int n_ = bcnt[bk];
    const int4* sb = st_meta + (size_t)bk * BCAP;
    const float4* sa = st_alpha + (size_t)bk * BCAP;
    const float2* sx = st_x + (size_t)bk * BCAP;
    for (int i = tid; i < n_; i += 256) {
        int4 r = sb[i];
        int li = r.y & 255;
        atomicAdd(&bins[li], 1);
        atomicAdd(&ls0[li], __int_as_float(r.z));
        atomicAdd(&ls1[li], __int_as_float(r.w));
    }
    __syncthreads();

    const int node = bk * BNODES + tid;
    const int v = (node < N_NODES) ? bins[tid] + 1 : 0;
    scan[tid] = v;
    __syncthreads();
    for (int off = 1; off < 256; off <<= 1) {
        int t = (tid >= off) ? scan[tid - off] : 0;
        __syncthreads();
        scan[tid] += t;
        __syncthreads();
    }
    const int o = bbase[bk] + scan[tid] - v;   // exclusive position
    if (node < N_NODES) {
        offs[node] = o;
        den[node] = 0.0f;
        float dgf = (float)max(bins[tid], 1);
        float u4 = ls0[tid] / dgf, u5 = ls1[tid] / dgf;
        int4 sl;
        sl.x = node; sl.y = node;
        sl.z = __float_as_int(u4); sl.w = __float_as_int(u5);
        epk[o] = sl;
        // self alpha (u2=u0, u3=u1)
        const float2 xn = *(const float2*)&xg[2 * node];
        const float u0 = xn.x, u1 = xn.y;
        float4 alf;
        #pragma unroll
        for (int h = 0; h < 4; ++h) {
            float ps = fmaf(u0, sA[h * 8] + sA[h * 8 + 2],
                       fmaf(u1, sA[h * 8 + 1] + sA[h * 8 + 3],
                       fmaf(u4, sA[h * 8 + 4], fmaf(u5, sA[h * 8 + 5], sA[h * 8 + 6]))));
            for (int c = 0; c < 64; ++c) {
                const float* wp = &sWp[c * 32 + h * 8];
                const float4 wa = *(const float4*)wp;
                const float4 wb = *(const float4*)(wp + 4);
                float tt = fmaf(u0, wa.x + wa.z, fmaf(u1, wa.y + wa.w,
                           fmaf(u4, wb.x, fmaf(u5, wb.y, wb.z))));
                ps = fmaf(fabsf(tt), wb.w, ps);
            }
            alf[h] = __expf(ps);
        }
        af[o] = *(float4*)&alf;
        xsrc[o] = xn;
    }
    cursor[tid] = o + 1;                       // first real-edge slot
    __syncthreads();

    for (int i = tid; i < n_; i += 256) {
        int4 r = sb[i];                        // L2-warm
        int pos = atomicAdd(&cursor[r.y & 255], 1);
        epk[pos] = r;
        af[pos] = sa[i];
        xsrc[pos] = sx[i];
    }
}

// ---------------- Fused: l1 softmax-sum (streaming) + h build + MFMA ----------

__global__ __launch_bounds__(256) void l1out_fused_kernel(
    const int* __restrict__ offs, const float4* __restrict__ af,
    const float2* __restrict__ xsrc,
    const float4* __restrict__ wpk4, const ushort16* __restrict__ Wt,
    const float* __restrict__ b2l, const float* __restrict__ b2r,
    ushort16* __restrict__ xl2b, ushort16* __restrict__ xr2b) {
    __shared__ short hlds[64 * 256];    // 32 KB bf16 h tile
    __shared__ float4 swpk[256];        // 4 KB build coeffs
    const int tid = threadIdx.x;
    const int n0 = blockIdx.x * 64;
    const int lane = tid & 63, w = tid >> 6;

    swpk[tid] = wpk4[tid];

    // ---- phase 0: streaming weighted sums for (node, head) ----
    const int nl = tid >> 2, head = tid & 3;
    const int node = n0 + nl;
    float S1 = 0.0f, S2 = 0.0f;
    if (node < N_NODES) {
        const int beg = offs[node], end = offs[node + 1];
        const float* afp = (const float*)af;
        float den = 0.0f, s1 = 0.0f, s2 = 0.0f;
        for (int e = beg; e < end; ++e) {
            float wt = afp[4 * e + head];
            float2 xs = xsrc[e];
            den += wt;
            s1 = fmaf(wt, xs.x, s1);
            s2 = fmaf(wt, xs.y, s2);
        }
        float inv = 1.0f / (den + 1e-16f);
        S1 = s1 * inv;
        S2 = s2 * inv;
    }
    __syncthreads();   // swpk ready

    // ---- phase 1: build h slice ----
    {
        const int kseg = head * 64;
        const int swz = (nl & 7) << 3;
        for (int i = 0; i < 8; ++i) {
            short8v hv;
            #pragma unroll
            for (int j = 0; j < 8; ++j) {
                float4 wv = swpk[kseg + i * 8 + j];
                float g = fmaf(wv.x, S1, fmaf(wv.y, S2, wv.z));
                g = g > 0.0f ? g : (__expf(g) - 1.0f);
                hv[j] = (short)f2bf(g);
            }
            *(short8v*)&hlds[(nl * 256 + kseg + i * 8) ^ swz] = hv;
        }
    }

    // ---- B fragments ----
    short8v bfrag[2][8];
    {
        const int bc = w * 32 + (lane & 15);
        const int k0 = (lane >> 4) * 8;
        #pragma unroll
        for (int ct = 0; ct < 2; ++ct)
            #pragma unroll
            for (int kb = 0; kb < 8; ++kb)
                bfrag[ct][kb] = *(const short8v*)&Wt[(size_t)(bc + ct * 16) * 256 + kb * 32 + k0];
    }
    __syncthreads();

    // ---- phase 2: MFMA ----
    f32x4 acc[4][2];
    #pragma unroll
    for (int rt = 0; rt < 4; ++rt)
        #pragma unroll
        for (int ct = 0; ct < 2; ++ct)
            acc[rt][ct] = (f32x4){0.0f, 0.0f, 0.0f, 0.0f};

    const int arow = lane & 15, ak0 = (lane >> 4) * 8;
    #pragma unroll
    for (int rt = 0; rt < 4; ++rt) {
        const int n = rt * 16 + arow;
        const int swz = (n & 7) << 3;
        #pragma unroll
        for (int kb = 0; kb < 8; ++kb) {
            short8v a = *(const short8v*)&hlds[(n * 256 + kb * 32 + ak0) ^ swz];
            acc[rt][0] = __builtin_amdgcn_mfma_f32_16x16x32_bf16(a, bfrag[0][kb], acc[rt][0], 0, 0, 0);
            acc[rt][1] = __builtin_amdgcn_mfma_f32_16x16x32_bf16(a, bfrag[1][kb], acc[rt][1], 0, 0, 0);
        }
    }

    // ---- epilogue ----
    #pragma unroll
    for (int ct = 0; ct < 2; ++ct) {
        const int c = w * 32 + ct * 16 + (lane & 15);
        const bool isL = (c < 64);
        const int cc = isL ? c : c - 64;
        const float bias = isL ? b2l[cc] : b2r[cc];
        ushort16* dst = isL ? xl2b : xr2b;
        #pragma unroll
        for (int rt = 0; rt < 4; ++rt)
            #pragma unroll
            for (int r = 0; r < 4; ++r) {
                int nn = n0 + rt * 16 + (lane >> 4) * 4 + r;
                if (nn < N_NODES) dst[nn * 64 + cc] = f2bf(acc[rt][ct][r] + bias);
            }
    }
}

// ---------------- Layer 2 logits: exp stored; den via LDS segmented reduction ----

__global__ __launch_bounds__(256) void l2_logit_kernel(
    const ushort16* __restrict__ xl2b, const ushort16* __restrict__ xr2b,
    const int4* __restrict__ epk,
    const float* __restrict__ W2e, const float* __restrict__ att2,
    float* __restrict__ alpha2, float* __restrict__ den) {
    __shared__ float sWe[128], satt[64];
    __shared__ float bins[L2BINS];
    const int tid = threadIdx.x;
    if (tid < 128) sWe[tid] = W2e[tid];
    if (tid < 64) satt[tid] = att2[tid];
    for (int i = tid; i < L2BINS; i += 256) bins[i] = 0.0f;
    const int base = blockIdx.x * L2CHUNK;
    const int d_first = epk[min(base, E_AUG - 1)].y;
    __syncthreads();

    const int lane = tid & 63, w = tid >> 6;
    const int cl = lane & 15, g = lane >> 4;
    const uint32* xlp = (const uint32*)xl2b;
    const uint32* xrp = (const uint32*)xr2b;

    for (int it = 0; it < L2CHUNK / 16; ++it) {
        const int e = base + it * 16 + w * 4 + g;
        if (e < E_AUG) {
            const int4 v = epk[e];
            const float ae0 = __int_as_float(v.z), ae1 = __int_as_float(v.w);
            float acc = 0.0f;
            #pragma unroll
            for (int q = 0; q < 2; ++q) {
                const int c2 = cl + q * 16;
                const uint32 ul = xlp[v.x * 32 + c2];
                const uint32 ur = xrp[v.y * 32 + c2];
                const int c0 = 2 * c2, c1 = 2 * c2 + 1;
                float xl0 = bf2f((ushort16)(ul & 0xffff)), xl1 = bf2f((ushort16)(ul >> 16));
                float xr0 = bf2f((ushort16)(ur & 0xffff)), xr1 = bf2f((ushort16)(ur >> 16));
                float t0 = xl0 + xr0 + fmaf(ae0, sWe[c0], ae1 * sWe[64 + c0]);
                float t1 = xl1 + xr1 + fmaf(ae0, sWe[c1], ae1 * sWe[64 + c1]);
                t0 = t0 > 0.0f ? t0 : 0.2f * t0;
                t1 = t1 > 0.0f ? t1 : 0.2f * t1;
                acc = fmaf(t0, satt[c0], fmaf(t1, satt[c1], acc));
            }
            #pragma unroll
            for (int off = 8; off; off >>= 1) acc += __shfl_xor(acc, off);
            if (cl == 0) {
                float wv = __expf(acc);
                alpha2[e] = wv;
                int rel = v.y - d_first;
                if (rel < L2BINS) atomicAdd(&bins[rel], wv);
                else atomicAdd(&den[v.y], wv);
            }
        }
    }
    __syncthreads();
    for (int i = tid; i < L2BINS; i += 256) {
        float b = bins[i];
        int node = d_first + i;
        if (b != 0.0f && node < N_NODES) atomicAdd(&den[node], b);
    }
}

// ---------------- Layer 2 pool: edge-parallel weighted accumulation ----------------

__global__ __launch_bounds__(256) void l2_pool_kernel(
    const ushort16* __restrict__ xl2b, const int4* __restrict__ epk,
    const float* __restrict__ alpha2, const float* __restrict__ den,
    float* __restrict__ pblock) {
    __shared__ float sp[16][64];
    const int tid = threadIdx.x;
    const int lane = tid & 63, w = tid >> 6;
    const int cl = lane & 15, g = lane >> 4;
    const int slot = w * 4 + g;
    const int base = blockIdx.x * L2CHUNK;
    const uint32* xlp = (const uint32*)xl2b;

    float a0 = 0.0f, a1 = 0.0f, a2 = 0.0f, a3 = 0.0f;
    for (int it = 0; it < L2CHUNK / 16; ++it) {
        const int e = base + it * 16 + w * 4 + g;
        if (e < E_AUG) {
            const int4 v = epk[e];
            const float coef = alpha2[e] / (den[v.y] + 1e-16f);
            const uint32 u0 = xlp[v.x * 32 + cl];
            const uint32 u1 = xlp[v.x * 32 + cl + 16];
            a0 = fmaf(coef, bf2f((ushort16)(u0 & 0xffff)), a0);
            a1 = fmaf(coef, bf2f((ushort16)(u0 >> 16)), a1);
            a2 = fmaf(coef, bf2f((ushort16)(u1 & 0xffff)), a2);
            a3 = fmaf(coef, bf2f((ushort16)(u1 >> 16)), a3);
        }
    }
    sp[slot][2 * cl] = a0;
    sp[slot][2 * cl + 1] = a1;
    sp[slot][2 * cl + 32] = a2;
    sp[slot][2 * cl + 33] = a3;
    __syncthreads();
    if (tid < 64) {
        float s = 0.0f;
        #pragma unroll
        for (int i = 0; i < 16; ++i) s += sp[i][tid];
        pblock[blockIdx.x * 64 + tid] = s;
    }
}

// ---------------- pool: partial (64 blocks) then final (1 block) ----------------

__global__ __launch_bounds__(256) void pool_partial_kernel(const float* __restrict__ pblock,
                                                           float* __restrict__ pfin) {
    __shared__ float s[256];
    int tid = threadIdx.x;
    int l = tid & 63, q = tid >> 6;
    float local = 0.0f;
    for (int r = blockIdx.x * 4 + q; r < NL2B; r += 64 * 4)
        local += pblock[r * 64 + l];
    s[tid] = local;
    __syncthreads();
    if (tid < 64) {
        float v = s[tid] + s[tid + 64] + s[tid + 128] + s[tid + 192];
        pfin[blockIdx.x * 64 + tid] = v;
    }
}

__global__ __launch_bounds__(256) void pool_final2_kernel(const float* __restrict__ pfin,
                                                          const float* __restrict__ bias2,
                                                          float* __restrict__ d_out) {
    __shared__ float s[256];
    int tid = threadIdx.x;
    int l = tid & 63, q = tid >> 6;
    float local = 0.0f;
    for (int r = q; r < 64; r += 4)
        local += pfin[r * 64 + l];
    s[tid] = local;
    __syncthreads();
    if (tid < 64) {
        float v = s[tid] + s[tid + 64] + s[tid + 128] + s[tid + 192];
        d_out[tid] = v * (1.0f / N_NODES) + bias2[tid];
    }
}

// ---------------- Host launch ----------------

extern "C" void kernel_launch(void* const* d_in, const int* in_sizes, int n_in,
                              void* d_out, int out_size, void* d_ws, size_t ws_size,
                              hipStream_t stream) {
    const float* x     = (const float*)d_in[0];
    const float* eattr = (const float*)d_in[1];
    const float* W1l   = (const float*)d_in[2];
    const float* b1l   = (const float*)d_in[3];
    const float* W1r   = (const float*)d_in[4];
    const float* b1r   = (const float*)d_in[5];
    const float* W1e   = (const float*)d_in[6];
    const float* att1  = (const float*)d_in[7];
    const float* bias1 = (const float*)d_in[8];
    const float* W2l   = (const float*)d_in[9];
    const float* b2l   = (const float*)d_in[10];
    const float* W2r   = (const float*)d_in[11];
    const float* b2r   = (const float*)d_in[12];
    const float* W2e   = (const float*)d_in[13];
    const float* att2  = (const float*)d_in[14];
    const float* bias2 = (const float*)d_in[15];
    const int*   ei    = (const int*)d_in[16];
    float* out = (float*)d_out;

    char* p = (char*)d_ws;
    auto alloc = [&](size_t bytes) -> void* {
        void* r = (void*)p;
        p += (bytes + 255) & ~(size_t)255;
        return r;
    };
    int*   bcnt   = (int*)alloc(256 * 4);
    int*   bbase  = (int*)alloc(256 * 4);
    int*   offs   = (int*)alloc((N_NODES + 1) * 4);
    float* den    = (float*)alloc(N_NODES * 4);
    int4*  st_meta  = (int4*)alloc((size_t)NBUCK * BCAP * 16);
    float4* st_alpha = (float4*)alloc((size_t)NBUCK * BCAP * 16);
    float2* st_x  = (float2*)alloc((size_t)NBUCK * BCAP * 8);
    int4*  epk    = (int4*)alloc((size_t)E_AUG * 16);
    float4* af    = (float4*)alloc((size_t)E_AUG * 16);
    float2* xsrc  = (float2*)alloc((size_t)E_AUG * 8);
    float* alpha2 = (float*)alloc((size_t)E_AUG * 4);
    float* Wpack  = (float*)alloc(256 * 8 * 4);
    float* Apack  = (float*)alloc(32 * 4);
    float4* wpk4  = (float4*)alloc(256 * 16);
    ushort16* Wt  = (ushort16*)alloc(128 * 256 * 2);
    ushort16* xl2b = (ushort16*)alloc((size_t)N_NODES * C2 * 2);
    ushort16* xr2b = (ushort16*)alloc((size_t)N_NODES * C2 * 2);
    float* pblock = (float*)alloc((size_t)NL2B * 64 * 4);
    float* pfin   = (float*)alloc((size_t)64 * 64 * 4);

    prep_kernel<<<128, 256, 0, stream>>>(W1l, b1l, W1r, b1r, W1e, att1, bias1, W2l, W2r,
                                         Wpack, Apack, wpk4, Wt, bcnt);

    pass1_kernel<<<HIST_BLOCKS, 256, 0, stream>>>(ei, eattr, x, Wpack, Apack,
                                                  st_meta, st_alpha, st_x, bcnt);

    bscan_kernel<<<1, 256, 0, stream>>>(bcnt, bbase, offs);

    buildk_kernel<<<NBUCK, 256, 0, stream>>>(st_meta, st_alpha, st_x, bcnt, bbase,
                                             x, Wpack, Apack,
                                             offs, den, epk, af, xsrc);

    l1out_fused_kernel<<<(N_NODES + 63) / 64, 256, 0, stream>>>(
        offs, af, xsrc, wpk4, Wt, b2l, b2r, xl2b, xr2b);

    l2_logit_kernel<<<NL2B, 256, 0, stream>>>(xl2b, xr2b, epk, W2e, att2, alpha2, den);

    l2_pool_kernel<<<NL2B, 256, 0, stream>>>(xl2b, epk, alpha2, den, pblock);

    pool_partial_kernel<<<64, 256, 0, stream>>>(pblock, pfin);
    pool_final2_kernel<<<1, 256, 0, stream>>>(pfin, bias2, out);
}